// Round 14
// baseline (239.250 us; speedup 1.0000x reference)
//
#include <hip/hip_runtime.h>

#define B 32
#define M 4096
#define N 8192
#define DC 10
#define NUM_ITERS 8
#define INV_TEMP 100.0f   // 1/TEMP, TEMP=0.01
#define ALPHA 100.0f
#define NB (N * B)        // 262144
#define MB (M * B)        // 131072
#define NBLK 512
#define TPB 256

// ---- grid barrier (no cooperative API) ----
// cnt at bar[0], gen at bar[32] (separate 128B lines). Data coherence across
// non-coherent XCD L2s comes from the __threadfence() pair (release: writeback
// dirty L2 to LLC; acquire: invalidate so later plain loads refetch) — data
// accesses themselves stay plain/cached (R9's per-access agent-scope ops were
// the 13x disaster). The gen read is ACQUIRE so it cannot reorder after the
// arrival increment (reorder => missed generation => deadlock).
__device__ __forceinline__ void grid_bar(unsigned* bar) {
    __syncthreads();
    if (threadIdx.x == 0) {
        __threadfence();   // release: drain + writeback our stores/atomics
        unsigned* cnt = bar;
        unsigned* gen = bar + 32;
        unsigned g = __hip_atomic_load(gen, __ATOMIC_ACQUIRE, __HIP_MEMORY_SCOPE_AGENT);
        unsigned a = __hip_atomic_fetch_add(cnt, 1u, __ATOMIC_RELAXED, __HIP_MEMORY_SCOPE_AGENT);
        if (a == NBLK - 1) {
            __hip_atomic_store(cnt, 0u, __ATOMIC_RELAXED, __HIP_MEMORY_SCOPE_AGENT);
            __hip_atomic_fetch_add(gen, 1u, __ATOMIC_RELEASE, __HIP_MEMORY_SCOPE_AGENT);
        } else {
            while (__hip_atomic_load(gen, __ATOMIC_RELAXED, __HIP_MEMORY_SCOPE_AGENT) == g)
                __builtin_amdgcn_s_sleep(8);
        }
        __threadfence();   // acquire: invalidate L1/L2 -> fresh LLC data below
    }
    __syncthreads();
}

// Persistent BP kernel: whole decode in ONE normal dispatch. 512 blocks x 256
// threads; __launch_bounds__(256,2) -> 2 blocks/CU needs 2 waves/SIMD and
// <=256 VGPR, satisfiable at ANY compiler allocation -> all 512 blocks
// co-resident by HW guarantee (LDS=0). One thread per (m,b), b innermost
// (R11's proven structure/math): nbrs-derived offsets, prior/pg/gamma at
// neighbors, syn sign, c2v messages and llrs replicas all live in REGISTERS
// across iterations. Per iteration per thread: 10 scattered gathers (Rb),
// 10 scattered atomics (Wb), 2 coalesced zeros (Zb); 1 grid barrier.
__global__ __launch_bounds__(TPB, 2) void bp_kernel(
    const float* __restrict__ syn,    // (B,M)
    const float* __restrict__ prior,  // (N,)
    const float* __restrict__ gamma,  // (N,)
    const int*   __restrict__ nbrs,   // (M,DC)
    float* __restrict__ A0,           // (N,B) accum rotation
    float* __restrict__ A1,
    float* __restrict__ A2,
    float* __restrict__ L,            // (N,B) llrs_6 + deg-0 prior
    float* __restrict__ out,          // (B,N)
    unsigned* __restrict__ bar)
{
    const int gid = blockIdx.x * TPB + threadIdx.x;   // 0..MB-1
    const int b = gid & 31;
    const int m = gid >> 5;

    // ---- prologue phase ----
    A0[gid] = 0.0f;  A0[gid + MB] = 0.0f;             // accum for t=0
    L[gid]  = prior[gid >> 5];                        // deg-0 vars: llrs==prior forever
    L[gid + MB] = prior[(gid + MB) >> 5];

    const float ssgn = 1.0f - 2.0f * syn[(size_t)b * M + m];

    int goff[DC];
    float pnb[DC], pgn[DC], gn[DC];
    #pragma unroll
    for (int i = 0; i < DC; ++i) {
        int nb = nbrs[m * DC + i];                    // broadcast within 32-lane group
        goff[i] = nb * B + b;
        float p = prior[nb], g = gamma[nb];
        pnb[i] = p; gn[i] = g; pgn[i] = (1.0f - g) * p;
    }

    float c2v[DC], ly[DC];                            // persistent register state

    float* Rb = A2; float* Wb = A0; float* Zb = A1;   // (R,W,Z) at t=0

    grid_bar(bar);

    for (int t = 0; t < NUM_ITERS; ++t) {
        Zb[gid] = 0.0f;  Zb[gid + MB] = 0.0f;         // accum for t+1 (own elements)

        float v[DC], lv[DC];
        if (t == 0) {
            #pragma unroll
            for (int i = 0; i < DC; ++i) { v[i] = pnb[i]; lv[i] = pnb[i]; }
        } else if (t == 1) {
            #pragma unroll
            for (int i = 0; i < DC; ++i) {
                float l = Rb[goff[i]] + pnb[i];       // llrs_0 replica (bit-identical)
                lv[i] = l; v[i] = l - c2v[i];
            }
        } else {
            #pragma unroll
            for (int i = 0; i < DC; ++i) {
                float l = Rb[goff[i]] + pgn[i] + gn[i] * ly[i];   // llrs_{t-1}
                lv[i] = l; v[i] = l - c2v[i];
            }
        }
        if (t == NUM_ITERS - 1) {
            #pragma unroll
            for (int i = 0; i < DC; ++i) L[goff[i]] = lv[i];  // llrs_6 (identical-value races benign)
        }
        #pragma unroll
        for (int i = 0; i < DC; ++i) ly[i] = lv[i];

        float s[DC], a[DC];
        #pragma unroll
        for (int i = 0; i < DC; ++i) {
            a[i] = fabsf(v[i]);
            float tt = __expf(-2.0f * ALPHA * a[i]);      // v_exp_f32
            float mag = (1.0f - tt) / (1.0f + tt);        // tanh(ALPHA*|v|)
            s[i] = copysignf(mag, v[i]);
        }

        // two smallest |v| and argmin
        float min1 = 3.4e38f, min2 = 3.4e38f;
        int am = 0;
        #pragma unroll
        for (int i = 0; i < DC; ++i) {
            if (a[i] < min1) { min2 = min1; min1 = a[i]; am = i; }
            else if (a[i] < min2) { min2 = a[i]; }
        }

        // prefix/suffix sign products for leave-one-out product
        float pre[DC + 1], suf[DC + 1];
        pre[0] = 1.0f;
        #pragma unroll
        for (int i = 0; i < DC; ++i) pre[i + 1] = pre[i] * s[i];
        suf[DC] = 1.0f;
        #pragma unroll
        for (int i = DC - 1; i >= 0; --i) suf[i] = suf[i + 1] * s[i];

        // softmin sums shifted by min1 (w[am] == 1 exactly)
        float w[DC];
        float se = 0.0f, sae = 0.0f;
        #pragma unroll
        for (int i = 0; i < DC; ++i) {
            w[i] = __expf((min1 - a[i]) * INV_TEMP);
            se  += w[i];
            sae += a[i] * w[i];
        }

        // uniform (branchless) min2-shifted sums for the argmin edge's LOO softmin
        float se2 = 0.0f, sae2 = 0.0f;
        #pragma unroll
        for (int j = 0; j < DC; ++j) {
            float e2 = __expf((min2 - a[j]) * INV_TEMP);
            e2 = (j != am) ? e2 : 0.0f;
            se2  += e2;
            sae2 += a[j] * e2;
        }
        float me_am = sae2 / se2;

        #pragma unroll
        for (int i = 0; i < DC; ++i) {
            float me = (i == am) ? me_am : (sae - a[i] * w[i]) / (se - w[i]);
            float o = ssgn * (pre[i] * suf[i + 1]) * me;
            c2v[i] = o;                                   // register state
            atomicAdd(&Wb[goff[i]], o);                   // device-scope
        }

        grid_bar(bar);

        float* tmp = Rb; Rb = Wb; Wb = Zb; Zb = tmp;      // rotate (R,W,Z)
    }

    // ---- final phase: Rb == accum_7, L == llrs_6 ----
    #pragma unroll
    for (int k = 0; k < 2; ++k) {
        int idx = gid + k * MB;                           // output index b*N+n
        int n  = idx & (N - 1);
        int bb = idx >> 13;
        int go = n * B + bb;
        float g = gamma[n];
        out[idx] = Rb[go] + (1.0f - g) * prior[n] + g * L[go];
    }
}

extern "C" void kernel_launch(void* const* d_in, const int* in_sizes, int n_in,
                              void* d_out, int out_size, void* d_ws, size_t ws_size,
                              hipStream_t stream) {
    const float* syn   = (const float*)d_in[0];   // (B,M)
    const float* prior = (const float*)d_in[1];   // (N,)
    const float* gamma = (const float*)d_in[2];   // (N,)
    const int*   nbrs  = (const int*)d_in[3];     // (M,DC)
    float* out = (float*)d_out;                   // (B,N)

    float* ws = (float*)d_ws;
    float* A0 = ws;
    float* A1 = ws + (size_t)NB;
    float* A2 = ws + 2 * (size_t)NB;
    float* L  = ws + 3 * (size_t)NB;
    unsigned* bar = (unsigned*)(ws + 4 * (size_t)NB);   // cnt@[0], gen@[32]

    // barrier state must start clean each call (first call sees 0xAA poison);
    // cnt returns to 0 after every barrier and gen is compared relatively, so
    // resetting both to 0 every call is replay-consistent.
    hipMemsetAsync(bar, 0, 64 * sizeof(unsigned), stream);

    bp_kernel<<<dim3(NBLK), dim3(TPB), 0, stream>>>(syn, prior, gamma, nbrs,
                                                    A0, A1, A2, L, out, bar);
}

// Round 15
// 77.471 us; speedup vs baseline: 3.0882x; 3.0882x over previous
//
#include <hip/hip_runtime.h>

#define B 32
#define M 4096
#define N 8192
#define DC 10
#define NUM_ITERS 8
#define INV_TEMP 100.0f   // 1/TEMP, TEMP=0.01
#define ALPHA 100.0f
#define NB (N * B)        // 262144
#define MB (M * B)        // 131072
#define NEDGE (M * DC)    // 40960

using f32x2 = __attribute__((ext_vector_type(2))) float;

// Prologue: zero accum A0, init L to prior (degree-0 variables: llrs_t == prior
// forever; final_kernel reads L for all n), build syn sign (M,B),
// pg = (1-gamma)*prior.
__global__ __launch_bounds__(256) void prologue_kernel(
    const float* __restrict__ syn,    // (B,M)
    const float* __restrict__ prior,  // (N,)
    const float* __restrict__ gamma,  // (N,)
    float* __restrict__ accumA,       // (N,B)
    float* __restrict__ L,            // (N,B)
    float* __restrict__ syn_t,        // (M,B)
    float* __restrict__ pg)           // (N,)
{
    int idx = blockIdx.x * blockDim.x + threadIdx.x;
    if (idx < NB) {
        accumA[idx] = 0.0f;
        L[idx] = prior[idx >> 5];
    }
    if (idx < MB) {
        int b = idx & 31, m = idx >> 5;
        syn_t[idx] = 1.0f - 2.0f * syn[(size_t)b * M + m];
    }
    if (idx < N) pg[idx] = (1.0f - gamma[idx]) * prior[idx];
}

// R15 = R12 structure (half-split wave: lanes 0-31 edges 0-4, lanes 32-63
// edges 5-9, b = lane&31; shfl_xor(32) combine; 1024 blocks = 16 waves/CU)
// + two subtractive trims:
//   WS=false at t=7: c2v_7 / ly_7 are dead -> skip all S stores and the
//     Z-zeroing of the unused next accumulator (saves ~11.5 MB on that dispatch).
//   nontemporal S stream: S is written once / read once per iteration with a
//     cold L2 at each boundary -> bypass L2 allocation, keep L2 for the
//     gather/atomic lines that ARE re-referenced within a dispatch.
// Math is bit-identical to R12 (absmax 0.0625).
// Per-edge persistent state S[(m*DC+i)*B+b] = (.x=c2v_{t-1}, .y=llrs_{t-2} replica).
// KIND 0: t=0   v2c = prior[nb]; no S read.
// KIND 1: t=1   l = R + prior[nb]       (S.y unused); v = l - S.x
// KIND 2: t>=2  l = R + pg + gamma*S.y;               v = l - S.x
// WL: write l (llrs_{t-1}) to L — only t=7, for final_kernel.
template <int KIND, bool WL, bool WS>
__global__ __launch_bounds__(256, 4) void check_kernel(
    const float*  __restrict__ syn_t,  // (M,B) sign form
    const float*  __restrict__ prior,  // (N,)
    const float*  __restrict__ pg,     // (N,)
    const float*  __restrict__ gamma,  // (N,)
    const int*    __restrict__ nbrs,   // (M,DC)
    const float*  __restrict__ R,      // accum_{t-1} (N,B)
    float*        __restrict__ W,      // accum_t (N,B), pre-zeroed
    float*        __restrict__ Z,      // accum buffer zeroed here for t+1
    float*        __restrict__ L,      // (N,B), written only when WL
    float2*       __restrict__ S)      // (M,DC,B) per-edge state
{
    const int tid  = threadIdx.x;
    const int lane = tid & 63;
    const int b    = lane & 31;
    const int h    = lane >> 5;                    // edge half: 0 -> 0..4, 1 -> 5..9
    const int m    = (blockIdx.x << 2) | (tid >> 6);

    // zero next iteration's accumulator (skipped at t=7: nothing consumes it)
    if (WS) __builtin_nontemporal_store(0.0f, &Z[blockIdx.x * 256 + tid]);

    const int* nr = nbrs + m * DC + 5 * h;
    float2* Sp = S + ((size_t)(m * DC + 5 * h)) * B + b;

    int nb[5];
    #pragma unroll
    for (int i = 0; i < 5; ++i) nb[i] = nr[i];     // broadcast within 32-lane group

    float v[5], lv[5];
    if (KIND == 0) {
        #pragma unroll
        for (int i = 0; i < 5; ++i) { v[i] = prior[nb[i]]; lv[i] = v[i]; }
    } else {
        #pragma unroll
        for (int i = 0; i < 5; ++i) {
            f32x2 st = __builtin_nontemporal_load(
                           (const f32x2*)&Sp[(size_t)i * B]);   // coalesced dwordx2 nt
            const int g = nb[i] * B + b;
            float l;
            if (KIND == 1) l = R[g] + prior[nb[i]];
            else           l = R[g] + pg[nb[i]] + gamma[nb[i]] * st[1];
            if (WL) __builtin_nontemporal_store(l, &L[g]);      // only t=7 (llrs_6)
            lv[i] = l;
            v[i] = l - st[0];
        }
    }

    float s[5], a[5];
    #pragma unroll
    for (int i = 0; i < 5; ++i) {
        a[i] = fabsf(v[i]);
        float tt = __expf(-2.0f * ALPHA * a[i]);    // v_exp_f32
        float mag = (1.0f - tt) / (1.0f + tt);      // tanh(ALPHA*|v|)
        s[i] = copysignf(mag, v[i]);
    }

    // own prefix/suffix sign products; full-product exchange with partner half
    float pre[6], suf[6];
    pre[0] = 1.0f;
    #pragma unroll
    for (int i = 0; i < 5; ++i) pre[i + 1] = pre[i] * s[i];
    suf[5] = 1.0f;
    #pragma unroll
    for (int i = 4; i >= 0; --i) suf[i] = suf[i + 1] * s[i];
    float prod_part = __shfl_xor(pre[5], 32, 64);

    // own two-smallest + argmin (global edge index)
    float m1o = 3.4e38f, m2o = 3.4e38f;
    int amo = 0;
    #pragma unroll
    for (int i = 0; i < 5; ++i) {
        if (a[i] < m1o) { m2o = m1o; m1o = a[i]; amo = i; }
        else if (a[i] < m2o) { m2o = a[i]; }
    }
    int amo_g = amo + 5 * h;

    float m1p   = __shfl_xor(m1o, 32, 64);
    float m2p   = __shfl_xor(m2o, 32, 64);
    int   amp_g = __shfl_xor(amo_g, 32, 64);

    // deterministic h0/h1-ordered merge (both halves compute identical results)
    float m1_0 = h ? m1p : m1o,  m1_1 = h ? m1o : m1p;
    int   am_0 = h ? amp_g : amo_g, am_1 = h ? amo_g : amp_g;
    float min1g = fminf(m1_0, m1_1);
    float min2g = fminf(fmaxf(m1_0, m1_1), fminf(m2o, m2p));
    int   am_g  = (m1_0 <= m1_1) ? am_0 : am_1;

    // min1g-shifted sums (w at the global argmin == 1 exactly)
    float w[5], se = 0.0f, sae = 0.0f;
    #pragma unroll
    for (int i = 0; i < 5; ++i) {
        w[i] = __expf((min1g - a[i]) * INV_TEMP);
        se  += w[i];
        sae += a[i] * w[i];
    }
    float se_tot  = se  + __shfl_xor(se, 32, 64);
    float sae_tot = sae + __shfl_xor(sae, 32, 64);

    // min2g-shifted sums excluding the global argmin (for its LOO softmin)
    float se2 = 0.0f, sae2 = 0.0f;
    #pragma unroll
    for (int i = 0; i < 5; ++i) {
        float e2 = __expf((min2g - a[i]) * INV_TEMP);
        e2 = ((i + 5 * h) != am_g) ? e2 : 0.0f;
        se2  += e2;
        sae2 += a[i] * e2;
    }
    float se2_tot  = se2  + __shfl_xor(se2, 32, 64);
    float sae2_tot = sae2 + __shfl_xor(sae2, 32, 64);
    float me_am = sae2_tot / se2_tot;

    float ssgn = syn_t[(m << 5) | b];

    #pragma unroll
    for (int i = 0; i < 5; ++i) {
        int gi = i + 5 * h;
        float me = (gi == am_g) ? me_am
                                : (sae_tot - a[i] * w[i]) / (se_tot - w[i]);
        float out = ssgn * (pre[i] * suf[i + 1] * prod_part) * me;
        if (WS) {
            f32x2 st; st[0] = out; st[1] = lv[i];
            __builtin_nontemporal_store(st, (f32x2*)&Sp[(size_t)i * B]);
        }
        atomicAdd(&W[nb[i] * B + b], out);
    }
}

// Epilogue: llrs_7 = accum_7 + pg + gamma*llrs_6, written transposed to d_out (B,N).
__global__ __launch_bounds__(256) void final_kernel(
    const float* __restrict__ R,     // accum_7 (N,B)
    const float* __restrict__ pg,    // (N,)
    const float* __restrict__ gamma, // (N,)
    const float* __restrict__ L,     // llrs_6 (N,B)
    float*       __restrict__ out)   // (B,N)
{
    int idx = blockIdx.x * blockDim.x + threadIdx.x;  // b*N + n (write-coalesced)
    if (idx >= NB) return;
    int n = idx & (N - 1);
    int b = idx >> 13;
    int goff = n * B + b;
    out[idx] = R[goff] + pg[n] + gamma[n] * L[goff];
}

extern "C" void kernel_launch(void* const* d_in, const int* in_sizes, int n_in,
                              void* d_out, int out_size, void* d_ws, size_t ws_size,
                              hipStream_t stream) {
    const float* syn   = (const float*)d_in[0];   // (B,M)
    const float* prior = (const float*)d_in[1];   // (N,)
    const float* gamma = (const float*)d_in[2];   // (N,)
    const int*   nbrs  = (const int*)d_in[3];     // (M,DC)
    float* out = (float*)d_out;                   // (B,N)

    float* ws = (float*)d_ws;
    float* A[3] = { ws, ws + NB, ws + 2 * (size_t)NB };   // accum rotation
    float* L    = ws + 3 * (size_t)NB;                    // NB (llrs_6 + deg-0 prior)
    float* syn_t= L + NB;                                 // MB
    float* pg   = syn_t + MB;                             // N
    float2* S   = (float2*)(pg + N);                      // NEDGE*B float2

    dim3 blk(256);
    dim3 pgrid((NB + 255) / 256);
    dim3 cgrid(M / 4);                                    // 1024 blocks, 64 thr/check

    prologue_kernel<<<pgrid, blk, 0, stream>>>(syn, prior, gamma, A[0], L, syn_t, pg);

    for (int t = 0; t < NUM_ITERS; ++t) {
        float* Rb = A[(t + 2) % 3];
        float* Wb = A[t % 3];
        float* Zb = A[(t + 1) % 3];
        if (t == 0) {
            check_kernel<0, false, true><<<cgrid, blk, 0, stream>>>(syn_t, prior, pg, gamma, nbrs,
                                                                    Rb, Wb, Zb, L, S);
        } else if (t == 1) {
            check_kernel<1, false, true><<<cgrid, blk, 0, stream>>>(syn_t, prior, pg, gamma, nbrs,
                                                                    Rb, Wb, Zb, L, S);
        } else if (t < NUM_ITERS - 1) {
            check_kernel<2, false, true><<<cgrid, blk, 0, stream>>>(syn_t, prior, pg, gamma, nbrs,
                                                                    Rb, Wb, Zb, L, S);
        } else {
            // t=7: write llrs_6 to L; skip dead S stores / Z zeroing
            check_kernel<2, true, false><<<cgrid, blk, 0, stream>>>(syn_t, prior, pg, gamma, nbrs,
                                                                    Rb, Wb, Zb, L, S);
        }
    }
    // after t=7: accum_7 = A[7%3] = A[1]; L holds llrs_6 (deg-0: prior)
    final_kernel<<<pgrid, blk, 0, stream>>>(A[1], pg, gamma, L, out);
}